// Round 11
// baseline (655.475 us; speedup 1.0000x reference)
//
#include <hip/hip_runtime.h>
#include <stdint.h>

#define IN_F 4096
#define OUT_F 4096
#define NROWS 8192
#define NT (IN_F / 64)   // 64 K-tiles of BK=64

typedef __attribute__((ext_vector_type(4))) int int4v;
typedef __attribute__((ext_vector_type(8))) int int8v;
typedef __attribute__((ext_vector_type(16))) float f32x16;
typedef __attribute__((ext_vector_type(4))) float floatx4;
typedef __attribute__((ext_vector_type(8))) short short8;

static __device__ __forceinline__ unsigned short f2bf(float f) {
  union { float f; unsigned int u; } v; v.f = f;
  unsigned int u = v.u;
  return (unsigned short)((u + 0x7FFFu + ((u >> 16) & 1u)) >> 16);
}

// ---- prepass 1 (fused, r10-validated): xb = fp8(x) AND ps = partial x.CP^T ----
__global__ __launch_bounds__(256) void xqs_mfma(const float* __restrict__ x,
                                                const float* __restrict__ cp,
                                                unsigned char* __restrict__ xb,
                                                float* __restrict__ ps) {
  __shared__ float red[4][16][16];
  const int b = blockIdx.x;
  const int rg = b >> 1, h = b & 1;
  const int tid = threadIdx.x;
  const int lane = tid & 63, wave = tid >> 6;
  const int l15 = lane & 15, l4 = lane >> 4;
  const int row = rg * 16 + l15;
  const int kbase = h * 2048 + wave * 512;

  floatx4 acc = {};
  #pragma unroll 4
  for (int it = 0; it < 16; ++it) {
    const int k0 = kbase + it * 32 + l4 * 8;
    const float4 xa = *(const float4*)(x + (size_t)row * IN_F + k0);
    const float4 xc = *(const float4*)(x + (size_t)row * IN_F + k0 + 4);
    int p0 = __builtin_amdgcn_cvt_pk_fp8_f32(xa.x, xa.y, 0, false);
    p0 = __builtin_amdgcn_cvt_pk_fp8_f32(xa.z, xa.w, p0, true);
    int p1 = __builtin_amdgcn_cvt_pk_fp8_f32(xc.x, xc.y, 0, false);
    p1 = __builtin_amdgcn_cvt_pk_fp8_f32(xc.z, xc.w, p1, true);
    *(uint2*)(xb + (size_t)row * IN_F + k0) = make_uint2((uint32_t)p0, (uint32_t)p1);
    union { unsigned short s[8]; short8 v; } af;
    af.s[0] = f2bf(xa.x); af.s[1] = f2bf(xa.y); af.s[2] = f2bf(xa.z); af.s[3] = f2bf(xa.w);
    af.s[4] = f2bf(xc.x); af.s[5] = f2bf(xc.y); af.s[6] = f2bf(xc.z); af.s[7] = f2bf(xc.w);
    union { unsigned short s[8]; short8 v; } bf;
    #pragma unroll
    for (int q = 0; q < 8; ++q) bf.s[q] = 0;
    if (l15 < 9) {
      const float4 ca = *(const float4*)(cp + (size_t)l15 * IN_F + k0);
      const float4 cc = *(const float4*)(cp + (size_t)l15 * IN_F + k0 + 4);
      bf.s[0] = f2bf(ca.x); bf.s[1] = f2bf(ca.y); bf.s[2] = f2bf(ca.z); bf.s[3] = f2bf(ca.w);
      bf.s[4] = f2bf(cc.x); bf.s[5] = f2bf(cc.y); bf.s[6] = f2bf(cc.z); bf.s[7] = f2bf(cc.w);
    }
    acc = __builtin_amdgcn_mfma_f32_16x16x32_bf16(af.v, bf.v, acc, 0, 0, 0);
  }
  #pragma unroll
  for (int r = 0; r < 4; ++r) red[wave][l4 * 4 + r][l15] = acc[r];
  __syncthreads();
  if (tid < 144) {
    const int rr = tid / 9, j = tid % 9;
    const float v = red[0][rr][j] + red[1][rr][j] + red[2][rr][j] + red[3][rr][j];
    ps[((size_t)h * NROWS + rg * 16 + rr) * 9 + j] = v;
  }
}

// ---- prepass 2: s = ps[0] + ps[1] ----
__global__ void s_reduce2(const float* __restrict__ ps, float* __restrict__ s) {
  const int row = blockIdx.x * 256 + threadIdx.x;
  #pragma unroll
  for (int j = 0; j < 9; ++j)
    s[row * 9 + j] = ps[(size_t)row * 9 + j] + ps[((size_t)NROWS + row) * 9 + j];
}

// ---- prepass 3: resid * 64 -> fp8 e4m3 ----
__global__ __launch_bounds__(256) void rq(const float* __restrict__ r,
                                          unsigned char* __restrict__ rb) {
  const int i = blockIdx.x * 256 + threadIdx.x;
  const float4* rv = (const float4*)r + (size_t)i * 4;
  uint32_t pk4[4];
  #pragma unroll
  for (int g = 0; g < 4; ++g) {
    float4 v = rv[g];
    int pk = __builtin_amdgcn_cvt_pk_fp8_f32(v.x * 64.f, v.y * 64.f, 0, false);
    pk = __builtin_amdgcn_cvt_pk_fp8_f32(v.z * 64.f, v.w * 64.f, pk, true);
    pk4[g] = (uint32_t)pk;
  }
  ((uint4*)rb)[i] = make_uint4(pk4[0], pk4[1], pk4[2], pk4[3]);
}

#define MFMA_FP8(d, av, bv) \
  d = __builtin_amdgcn_mfma_scale_f32_32x32x64_f8f6f4( \
      av, bv, d, 0, 0, 0, 0x7F7F7F7F, 0, 0x7F7F7F7F)

// ---- main GEMM: y = (xb.rb^T)/64 + spline(s) + bias ----
// Round-8 skeleton (validated: triple-buffer, distance-2 prefetch, counted
// vmcnt, 1 barrier/interval, setprio) scaled to 256x128 tile, 8 waves
// (4M x 2N, each 64x64 quadrant, same acc[2][2] / ldf / stage geometry).
// LDS = 3 bufs x 24 KB = 72 KB -> 2 blocks/CU (16 waves/CU).
// Staged bytes drop 2.0 GB -> 1.5 GB; MFMA per block-interval 16 -> 32.
__global__ __launch_bounds__(512, 4) void gemm_fp8(
    const unsigned char* __restrict__ A,   // xb [8192][4096]
    const unsigned char* __restrict__ B,   // rb [4096][4096] (x64)
    const float* __restrict__ S,           // s [8192][9]
    const float* __restrict__ bias,
    float* __restrict__ C) {
  __shared__ unsigned char lds[3 * 24576];   // [buf][A 16K | B 8K]

  const int tid = threadIdx.x;
  const int lane = tid & 63;
  const int wave = tid >> 6;    // 0..7
  const int wr = wave >> 1;     // M quarter (64 rows)
  const int wn = wave & 1;      // N half (64 cols)
  const int l31 = lane & 31;
  const int lh = lane >> 5;

  // XCD-aware swizzle (1024 % 8 == 0 -> bijective)
  const int bs = (blockIdx.x & 7) * 128 + (blockIdx.x >> 3);
  const int bm = bs >> 5;       // 32 M-tiles
  const int bn = bs & 31;       // 32 N-tiles
  const size_t row0 = (size_t)bm * 256;
  const size_t col0 = (size_t)bn * 128;

  // stage 128 fp8-rows [half*128, half*128+128) of A(ab=0)/B(ab=1), tile kt
  // -> buf. r5-verified packing: 2 rows per 128B LDS line, 16B-slot swizzle
  // sl^=(L&7); linear LDS dest, inverse-swizzled global source. 512 threads,
  // one 16B gload_lds each = 8 KB per call.
  auto stage = [&](int buf, int ab, int half, const unsigned char* __restrict__ src,
                   size_t grow0, int kt) {
    const int L = tid >> 3;                       // line within call (0..63)
    const int ls = (tid & 7) ^ (L & 7);           // logical slot in line
    const int r = half * 128 + 2 * L + (ls >> 2);
    const unsigned char* g = src + (grow0 + r) * (size_t)IN_F + kt * 64 + (ls & 3) * 16;
    unsigned char* d = lds + buf * 24576 + ab * 16384 + half * 8192 + (tid >> 6) * 1024;
    __builtin_amdgcn_global_load_lds(
        (const __attribute__((address_space(1))) void*)g,
        (__attribute__((address_space(3))) void*)d, 16, 0, 0);
  };
  auto stage_tile = [&](int buf, int kt) {   // 3 issues per thread
    stage(buf, 0, 0, A, row0, kt); stage(buf, 0, 1, A, row0, kt);
    stage(buf, 1, 0, B, col0, kt);
  };
  // one b128 of a 32-row operand (r5-verified geometry)
  auto ldf = [&](int buf, int ab, int rbase, int s2) -> int4v {
    const int r = rbase + l31;
    const int sl = (r & 1) * 4 + lh * 2 + s2;
    const int L = r >> 1;
    return *(const int4v*)&lds[buf * 24576 + ab * 16384 + L * 128 + ((sl ^ (L & 7)) * 16)];
  };

  f32x16 acc[2][2] = {};

  // prologue: stage tiles 0 and 1; wait tile 0 (6 in flight -> vmcnt(3))
  stage_tile(0, 0);
  stage_tile(1, 1);
  asm volatile("s_waitcnt vmcnt(3)" ::: "memory");
  __builtin_amdgcn_s_barrier();

  int cur = 0, nx2 = 2;   // t%3, (t+2)%3 rotating
  #pragma unroll 1
  for (int t = 0; t < NT; ++t) {
    const bool more = (t + 2 < NT);
    if (more) stage_tile(nx2, t + 2);

    union { int8v v8; int4v v4[2]; } a0, a1, b0, b1;
    a0.v4[0] = ldf(cur, 0, wr * 64 + 0,  0); a0.v4[1] = ldf(cur, 0, wr * 64 + 0,  1);
    a1.v4[0] = ldf(cur, 0, wr * 64 + 32, 0); a1.v4[1] = ldf(cur, 0, wr * 64 + 32, 1);
    b0.v4[0] = ldf(cur, 1, wn * 64 + 0,  0); b0.v4[1] = ldf(cur, 1, wn * 64 + 0,  1);
    b1.v4[0] = ldf(cur, 1, wn * 64 + 32, 0); b1.v4[1] = ldf(cur, 1, wn * 64 + 32, 1);
    __builtin_amdgcn_s_setprio(1);
    MFMA_FP8(acc[0][0], a0.v8, b0.v8);
    MFMA_FP8(acc[0][1], a0.v8, b1.v8);
    MFMA_FP8(acc[1][0], a1.v8, b0.v8);
    MFMA_FP8(acc[1][1], a1.v8, b1.v8);
    __builtin_amdgcn_s_setprio(0);

    asm volatile("s_waitcnt lgkmcnt(0)" ::: "memory");
    if (more) {
      asm volatile("s_waitcnt vmcnt(3)" ::: "memory");   // tile t+1 landed
    } else {
      asm volatile("s_waitcnt vmcnt(0)" ::: "memory");   // tail drain
    }
    __builtin_amdgcn_s_barrier();

    cur = (cur == 2) ? 0 : cur + 1;
    nx2 = (nx2 == 2) ? 0 : nx2 + 1;
  }

  // epilogue: y = acc/64 + Catmull-Rom(o) . s[n][j-1..j+2] + bias[o]
  // D layout (32x32): col = lane&31, row = (reg&3) + 8*(reg>>2) + 4*(lane>>5)
  const float inv64 = 0.015625f;
  #pragma unroll
  for (int ni = 0; ni < 2; ++ni) {
    const int o = (int)col0 + wn * 64 + ni * 32 + l31;
    float ts = ((float)o / 4095.0f) * 8.0f;
    int j = (int)floorf(ts);
    j = j < 1 ? 1 : (j > 6 ? 6 : j);
    float t = ts - (float)j;
    float t2 = t * t, t3 = t2 * t;
    const float c0 = -0.5f * t3 + t2 - 0.5f * t;
    const float c1 = 1.5f * t3 - 2.5f * t2 + 1.0f;
    const float c2 = -1.5f * t3 + 2.0f * t2 + 0.5f * t;
    const float c3 = 0.5f * t3 - 0.5f * t2;
    const float bv = bias[o];
    #pragma unroll
    for (int mi = 0; mi < 2; ++mi) {
      #pragma unroll
      for (int rg = 0; rg < 16; ++rg) {
        const int n = (int)row0 + wr * 64 + mi * 32 + (rg & 3) + 8 * (rg >> 2) + 4 * lh;
        const float* sr = S + n * 9 + (j - 1);
        C[(size_t)n * OUT_F + o] =
            acc[mi][ni][rg] * inv64 + c0 * sr[0] + c1 * sr[1] + c2 * sr[2] + c3 * sr[3] + bv;
      }
    }
  }
}

// ---- safety net: fp32 tiled GEMM w/ on-the-fly weight ----
static __device__ __forceinline__ void cr_coeffs(int o, int& j, float& c0, float& c1,
                                                 float& c2, float& c3) {
  float ts = ((float)o / 4095.0f) * 8.0f;
  j = (int)floorf(ts);
  j = j < 1 ? 1 : (j > 6 ? 6 : j);
  float t = ts - (float)j;
  float t2 = t * t, t3 = t2 * t;
  c0 = -0.5f * t3 + t2 - 0.5f * t;
  c1 = 1.5f * t3 - 2.5f * t2 + 1.0f;
  c2 = -1.5f * t3 + 2.0f * t2 + 0.5f * t;
  c3 = 0.5f * t3 - 0.5f * t2;
}

__global__ void fallback_gemm(const float* __restrict__ x, const float* __restrict__ cp,
                              const float* __restrict__ resid, const float* __restrict__ bias,
                              float* __restrict__ out) {
  __shared__ float xs[64][32];
  __shared__ float ws[64][33];
  const int tid = threadIdx.x;
  const int bm = blockIdx.x / (OUT_F / 64);
  const int bn = blockIdx.x % (OUT_F / 64);
  const int row0 = bm * 64, col0 = bn * 64;
  const int tr = tid >> 4, tc = tid & 15;
  float acc[4][4] = {};
  for (int k0 = 0; k0 < IN_F; k0 += 32) {
    #pragma unroll
    for (int q = 0; q < 8; ++q) {
      int e = q * 256 + tid;
      int r = e >> 5, cc = e & 31;
      xs[r][cc] = x[(size_t)(row0 + r) * IN_F + k0 + cc];
      int o = col0 + r;
      int j; float c0, c1, c2, c3;
      cr_coeffs(o, j, c0, c1, c2, c3);
      size_t ci = (size_t)(j - 1) * IN_F + k0 + cc;
      ws[r][cc] = c0 * cp[ci] + c1 * cp[ci + IN_F] + c2 * cp[ci + 2 * IN_F] +
                  c3 * cp[ci + 3 * IN_F] + resid[(size_t)o * IN_F + k0 + cc];
    }
    __syncthreads();
    #pragma unroll
    for (int kk = 0; kk < 32; ++kk) {
      float xv[4], wv[4];
      #pragma unroll
      for (int i = 0; i < 4; ++i) xv[i] = xs[tr * 4 + i][kk];
      #pragma unroll
      for (int i = 0; i < 4; ++i) wv[i] = ws[tc * 4 + i][kk];
      #pragma unroll
      for (int i = 0; i < 4; ++i)
        #pragma unroll
        for (int jj = 0; jj < 4; ++jj) acc[i][jj] += xv[i] * wv[jj];
    }
    __syncthreads();
  }
  #pragma unroll
  for (int i = 0; i < 4; ++i)
    #pragma unroll
    for (int jj = 0; jj < 4; ++jj) {
      int row = row0 + tr * 4 + i, col = col0 + tc * 4 + jj;
      out[(size_t)row * OUT_F + col] = acc[i][jj] + bias[col];
    }
}

extern "C" void kernel_launch(void* const* d_in, const int* in_sizes, int n_in,
                              void* d_out, int out_size, void* d_ws, size_t ws_size,
                              hipStream_t stream) {
  const float* x = (const float*)d_in[0];
  const float* cp = (const float*)d_in[1];
  const float* resid = (const float*)d_in[2];
  const float* bias = (const float*)d_in[3];
  float* out = (float*)d_out;

  const size_t xb_b = (size_t)NROWS * IN_F;        // 33,554,432
  const size_t rb_b = (size_t)OUT_F * IN_F;        // 16,777,216
  const size_t s_b = (size_t)NROWS * 9 * 4;        // 294,912
  const size_t ps_b = (size_t)2 * NROWS * 9 * 4;   // 589,824

  if (ws_size >= xb_b + rb_b + s_b + ps_b) {
    unsigned char* xb = (unsigned char*)d_ws;
    unsigned char* rb = xb + xb_b;
    float* s = (float*)(rb + rb_b);
    float* ps = (float*)((unsigned char*)s + s_b);
    hipLaunchKernelGGL(xqs_mfma, dim3(1024), dim3(256), 0, stream, x, cp, xb, ps);
    hipLaunchKernelGGL(s_reduce2, dim3(32), dim3(256), 0, stream, ps, s);
    hipLaunchKernelGGL(rq, dim3(4096), dim3(256), 0, stream, resid, rb);
    // (8192/256) * (4096/128) = 32*32 = 1024 blocks, 512 threads
    hipLaunchKernelGGL(gemm_fp8, dim3(1024), dim3(512), 0, stream, xb, rb, s, bias, out);
  } else {
    hipLaunchKernelGGL(fallback_gemm, dim3((NROWS / 64) * (OUT_F / 64)), dim3(256), 0,
                       stream, x, cp, resid, bias, out);
  }
}

// Round 12
// 230.504 us; speedup vs baseline: 2.8437x; 2.8437x over previous
//
#include <hip/hip_runtime.h>
#include <stdint.h>

#define IN_F 4096
#define OUT_F 4096
#define NROWS 8192
#define NT (IN_F / 64)   // 64 K-tiles of BK=64

typedef __attribute__((ext_vector_type(4))) int int4v;
typedef __attribute__((ext_vector_type(8))) int int8v;
typedef __attribute__((ext_vector_type(16))) float f32x16;
typedef __attribute__((ext_vector_type(4))) float floatx4;
typedef __attribute__((ext_vector_type(8))) short short8;

static __device__ __forceinline__ unsigned short f2bf(float f) {
  union { float f; unsigned int u; } v; v.f = f;
  unsigned int u = v.u;
  return (unsigned short)((u + 0x7FFFu + ((u >> 16) & 1u)) >> 16);
}

// ---- prepass 1 (fused, r10-validated): xb = fp8(x) AND ps = partial x.CP^T ----
__global__ __launch_bounds__(256) void xqs_mfma(const float* __restrict__ x,
                                                const float* __restrict__ cp,
                                                unsigned char* __restrict__ xb,
                                                float* __restrict__ ps) {
  __shared__ float red[4][16][16];
  const int b = blockIdx.x;
  const int rg = b >> 1, h = b & 1;
  const int tid = threadIdx.x;
  const int lane = tid & 63, wave = tid >> 6;
  const int l15 = lane & 15, l4 = lane >> 4;
  const int row = rg * 16 + l15;
  const int kbase = h * 2048 + wave * 512;

  floatx4 acc = {};
  #pragma unroll 4
  for (int it = 0; it < 16; ++it) {
    const int k0 = kbase + it * 32 + l4 * 8;
    const float4 xa = *(const float4*)(x + (size_t)row * IN_F + k0);
    const float4 xc = *(const float4*)(x + (size_t)row * IN_F + k0 + 4);
    int p0 = __builtin_amdgcn_cvt_pk_fp8_f32(xa.x, xa.y, 0, false);
    p0 = __builtin_amdgcn_cvt_pk_fp8_f32(xa.z, xa.w, p0, true);
    int p1 = __builtin_amdgcn_cvt_pk_fp8_f32(xc.x, xc.y, 0, false);
    p1 = __builtin_amdgcn_cvt_pk_fp8_f32(xc.z, xc.w, p1, true);
    *(uint2*)(xb + (size_t)row * IN_F + k0) = make_uint2((uint32_t)p0, (uint32_t)p1);
    union { unsigned short s[8]; short8 v; } af;
    af.s[0] = f2bf(xa.x); af.s[1] = f2bf(xa.y); af.s[2] = f2bf(xa.z); af.s[3] = f2bf(xa.w);
    af.s[4] = f2bf(xc.x); af.s[5] = f2bf(xc.y); af.s[6] = f2bf(xc.z); af.s[7] = f2bf(xc.w);
    union { unsigned short s[8]; short8 v; } bf;
    #pragma unroll
    for (int q = 0; q < 8; ++q) bf.s[q] = 0;
    if (l15 < 9) {
      const float4 ca = *(const float4*)(cp + (size_t)l15 * IN_F + k0);
      const float4 cc = *(const float4*)(cp + (size_t)l15 * IN_F + k0 + 4);
      bf.s[0] = f2bf(ca.x); bf.s[1] = f2bf(ca.y); bf.s[2] = f2bf(ca.z); bf.s[3] = f2bf(ca.w);
      bf.s[4] = f2bf(cc.x); bf.s[5] = f2bf(cc.y); bf.s[6] = f2bf(cc.z); bf.s[7] = f2bf(cc.w);
    }
    acc = __builtin_amdgcn_mfma_f32_16x16x32_bf16(af.v, bf.v, acc, 0, 0, 0);
  }
  #pragma unroll
  for (int r = 0; r < 4; ++r) red[wave][l4 * 4 + r][l15] = acc[r];
  __syncthreads();
  if (tid < 144) {
    const int rr = tid / 9, j = tid % 9;
    const float v = red[0][rr][j] + red[1][rr][j] + red[2][rr][j] + red[3][rr][j];
    ps[((size_t)h * NROWS + rg * 16 + rr) * 9 + j] = v;
  }
}

// ---- prepass 2: s = ps[0] + ps[1] ----
__global__ void s_reduce2(const float* __restrict__ ps, float* __restrict__ s) {
  const int row = blockIdx.x * 256 + threadIdx.x;
  #pragma unroll
  for (int j = 0; j < 9; ++j)
    s[row * 9 + j] = ps[(size_t)row * 9 + j] + ps[((size_t)NROWS + row) * 9 + j];
}

// ---- prepass 3: resid * 64 -> fp8 e4m3 ----
__global__ __launch_bounds__(256) void rq(const float* __restrict__ r,
                                          unsigned char* __restrict__ rb) {
  const int i = blockIdx.x * 256 + threadIdx.x;
  const float4* rv = (const float4*)r + (size_t)i * 4;
  uint32_t pk4[4];
  #pragma unroll
  for (int g = 0; g < 4; ++g) {
    float4 v = rv[g];
    int pk = __builtin_amdgcn_cvt_pk_fp8_f32(v.x * 64.f, v.y * 64.f, 0, false);
    pk = __builtin_amdgcn_cvt_pk_fp8_f32(v.z * 64.f, v.w * 64.f, pk, true);
    pk4[g] = (uint32_t)pk;
  }
  ((uint4*)rb)[i] = make_uint4(pk4[0], pk4[1], pk4[2], pk4[3]);
}

#define MFMA_FP8(d, av, bv) \
  d = __builtin_amdgcn_mfma_scale_f32_32x32x64_f8f6f4( \
      av, bv, d, 0, 0, 0, 0x7F7F7F7F, 0, 0x7F7F7F7F)

// ---- main GEMM: y = (xb.rb^T)/64 + spline(s) + bias ----
// Round-11 structure with the launch-bounds fix: 256x128 tile, 8 waves
// (4M x 2N, 64x64 quadrants), triple-buffered 72 KB LDS, distance-2
// prefetch, counted vmcnt(3), 1 barrier/interval.
// __launch_bounds__(512, 2): 2 blocks/CU -> 16 waves/CU -> VGPR cap 128
// (round 11's (512,4) capped VGPR at 64 -> acc spill -> 1.1 GB scratch).
__global__ __launch_bounds__(512, 2) void gemm_fp8(
    const unsigned char* __restrict__ A,   // xb [8192][4096]
    const unsigned char* __restrict__ B,   // rb [4096][4096] (x64)
    const float* __restrict__ S,           // s [8192][9]
    const float* __restrict__ bias,
    float* __restrict__ C) {
  __shared__ unsigned char lds[3 * 24576];   // [buf][A 16K | B 8K]

  const int tid = threadIdx.x;
  const int lane = tid & 63;
  const int wave = tid >> 6;    // 0..7
  const int wr = wave >> 1;     // M quarter (64 rows)
  const int wn = wave & 1;      // N half (64 cols)
  const int l31 = lane & 31;
  const int lh = lane >> 5;

  // XCD-aware swizzle (1024 % 8 == 0 -> bijective)
  const int bs = (blockIdx.x & 7) * 128 + (blockIdx.x >> 3);
  const int bm = bs >> 5;       // 32 M-tiles
  const int bn = bs & 31;       // 32 N-tiles
  const size_t row0 = (size_t)bm * 256;
  const size_t col0 = (size_t)bn * 128;

  // stage 128 fp8-rows [half*128, half*128+128) of A(ab=0)/B(ab=1), tile kt
  // -> buf. r5-verified packing: 2 rows per 128B LDS line, 16B-slot swizzle
  // sl^=(L&7); linear LDS dest, inverse-swizzled global source.
  auto stage = [&](int buf, int ab, int half, const unsigned char* __restrict__ src,
                   size_t grow0, int kt) {
    const int L = tid >> 3;                       // line within call (0..63)
    const int ls = (tid & 7) ^ (L & 7);           // logical slot in line
    const int r = half * 128 + 2 * L + (ls >> 2);
    const unsigned char* g = src + (grow0 + r) * (size_t)IN_F + kt * 64 + (ls & 3) * 16;
    unsigned char* d = lds + buf * 24576 + ab * 16384 + half * 8192 + (tid >> 6) * 1024;
    __builtin_amdgcn_global_load_lds(
        (const __attribute__((address_space(1))) void*)g,
        (__attribute__((address_space(3))) void*)d, 16, 0, 0);
  };
  auto stage_tile = [&](int buf, int kt) {   // 3 issues per thread
    stage(buf, 0, 0, A, row0, kt); stage(buf, 0, 1, A, row0, kt);
    stage(buf, 1, 0, B, col0, kt);
  };
  // one b128 of a 32-row operand (r5-verified geometry)
  auto ldf = [&](int buf, int ab, int rbase, int s2) -> int4v {
    const int r = rbase + l31;
    const int sl = (r & 1) * 4 + lh * 2 + s2;
    const int L = r >> 1;
    return *(const int4v*)&lds[buf * 24576 + ab * 16384 + L * 128 + ((sl ^ (L & 7)) * 16)];
  };

  f32x16 acc[2][2] = {};

  // prologue: stage tiles 0 and 1; wait tile 0 (6 in flight -> vmcnt(3))
  stage_tile(0, 0);
  stage_tile(1, 1);
  asm volatile("s_waitcnt vmcnt(3)" ::: "memory");
  __builtin_amdgcn_s_barrier();

  int cur = 0, nx2 = 2;   // t%3, (t+2)%3 rotating
  #pragma unroll 1
  for (int t = 0; t < NT; ++t) {
    const bool more = (t + 2 < NT);
    if (more) stage_tile(nx2, t + 2);

    union { int8v v8; int4v v4[2]; } a0, a1, b0, b1;
    a0.v4[0] = ldf(cur, 0, wr * 64 + 0,  0); a0.v4[1] = ldf(cur, 0, wr * 64 + 0,  1);
    a1.v4[0] = ldf(cur, 0, wr * 64 + 32, 0); a1.v4[1] = ldf(cur, 0, wr * 64 + 32, 1);
    b0.v4[0] = ldf(cur, 1, wn * 64 + 0,  0); b0.v4[1] = ldf(cur, 1, wn * 64 + 0,  1);
    b1.v4[0] = ldf(cur, 1, wn * 64 + 32, 0); b1.v4[1] = ldf(cur, 1, wn * 64 + 32, 1);
    __builtin_amdgcn_s_setprio(1);
    MFMA_FP8(acc[0][0], a0.v8, b0.v8);
    MFMA_FP8(acc[0][1], a0.v8, b1.v8);
    MFMA_FP8(acc[1][0], a1.v8, b0.v8);
    MFMA_FP8(acc[1][1], a1.v8, b1.v8);
    __builtin_amdgcn_s_setprio(0);

    asm volatile("s_waitcnt lgkmcnt(0)" ::: "memory");
    if (more) {
      asm volatile("s_waitcnt vmcnt(3)" ::: "memory");   // tile t+1 landed
    } else {
      asm volatile("s_waitcnt vmcnt(0)" ::: "memory");   // tail drain
    }
    __builtin_amdgcn_s_barrier();

    cur = (cur == 2) ? 0 : cur + 1;
    nx2 = (nx2 == 2) ? 0 : nx2 + 1;
  }

  // epilogue: y = acc/64 + Catmull-Rom(o) . s[n][j-1..j+2] + bias[o]
  // D layout (32x32): col = lane&31, row = (reg&3) + 8*(reg>>2) + 4*(lane>>5)
  const float inv64 = 0.015625f;
  #pragma unroll
  for (int ni = 0; ni < 2; ++ni) {
    const int o = (int)col0 + wn * 64 + ni * 32 + l31;
    float ts = ((float)o / 4095.0f) * 8.0f;
    int j = (int)floorf(ts);
    j = j < 1 ? 1 : (j > 6 ? 6 : j);
    float t = ts - (float)j;
    float t2 = t * t, t3 = t2 * t;
    const float c0 = -0.5f * t3 + t2 - 0.5f * t;
    const float c1 = 1.5f * t3 - 2.5f * t2 + 1.0f;
    const float c2 = -1.5f * t3 + 2.0f * t2 + 0.5f * t;
    const float c3 = 0.5f * t3 - 0.5f * t2;
    const float bv = bias[o];
    #pragma unroll
    for (int mi = 0; mi < 2; ++mi) {
      #pragma unroll
      for (int rg = 0; rg < 16; ++rg) {
        const int n = (int)row0 + wr * 64 + mi * 32 + (rg & 3) + 8 * (rg >> 2) + 4 * lh;
        const float* sr = S + n * 9 + (j - 1);
        C[(size_t)n * OUT_F + o] =
            acc[mi][ni][rg] * inv64 + c0 * sr[0] + c1 * sr[1] + c2 * sr[2] + c3 * sr[3] + bv;
      }
    }
  }
}

// ---- safety net: fp32 tiled GEMM w/ on-the-fly weight ----
static __device__ __forceinline__ void cr_coeffs(int o, int& j, float& c0, float& c1,
                                                 float& c2, float& c3) {
  float ts = ((float)o / 4095.0f) * 8.0f;
  j = (int)floorf(ts);
  j = j < 1 ? 1 : (j > 6 ? 6 : j);
  float t = ts - (float)j;
  float t2 = t * t, t3 = t2 * t;
  c0 = -0.5f * t3 + t2 - 0.5f * t;
  c1 = 1.5f * t3 - 2.5f * t2 + 1.0f;
  c2 = -1.5f * t3 + 2.0f * t2 + 0.5f * t;
  c3 = 0.5f * t3 - 0.5f * t2;
}

__global__ void fallback_gemm(const float* __restrict__ x, const float* __restrict__ cp,
                              const float* __restrict__ resid, const float* __restrict__ bias,
                              float* __restrict__ out) {
  __shared__ float xs[64][32];
  __shared__ float ws[64][33];
  const int tid = threadIdx.x;
  const int bm = blockIdx.x / (OUT_F / 64);
  const int bn = blockIdx.x % (OUT_F / 64);
  const int row0 = bm * 64, col0 = bn * 64;
  const int tr = tid >> 4, tc = tid & 15;
  float acc[4][4] = {};
  for (int k0 = 0; k0 < IN_F; k0 += 32) {
    #pragma unroll
    for (int q = 0; q < 8; ++q) {
      int e = q * 256 + tid;
      int r = e >> 5, cc = e & 31;
      xs[r][cc] = x[(size_t)(row0 + r) * IN_F + k0 + cc];
      int o = col0 + r;
      int j; float c0, c1, c2, c3;
      cr_coeffs(o, j, c0, c1, c2, c3);
      size_t ci = (size_t)(j - 1) * IN_F + k0 + cc;
      ws[r][cc] = c0 * cp[ci] + c1 * cp[ci + IN_F] + c2 * cp[ci + 2 * IN_F] +
                  c3 * cp[ci + 3 * IN_F] + resid[(size_t)o * IN_F + k0 + cc];
    }
    __syncthreads();
    #pragma unroll
    for (int kk = 0; kk < 32; ++kk) {
      float xv[4], wv[4];
      #pragma unroll
      for (int i = 0; i < 4; ++i) xv[i] = xs[tr * 4 + i][kk];
      #pragma unroll
      for (int i = 0; i < 4; ++i) wv[i] = ws[tc * 4 + i][kk];
      #pragma unroll
      for (int i = 0; i < 4; ++i)
        #pragma unroll
        for (int jj = 0; jj < 4; ++jj) acc[i][jj] += xv[i] * wv[jj];
    }
    __syncthreads();
  }
  #pragma unroll
  for (int i = 0; i < 4; ++i)
    #pragma unroll
    for (int jj = 0; jj < 4; ++jj) {
      int row = row0 + tr * 4 + i, col = col0 + tc * 4 + jj;
      out[(size_t)row * OUT_F + col] = acc[i][jj] + bias[col];
    }
}

extern "C" void kernel_launch(void* const* d_in, const int* in_sizes, int n_in,
                              void* d_out, int out_size, void* d_ws, size_t ws_size,
                              hipStream_t stream) {
  const float* x = (const float*)d_in[0];
  const float* cp = (const float*)d_in[1];
  const float* resid = (const float*)d_in[2];
  const float* bias = (const float*)d_in[3];
  float* out = (float*)d_out;

  const size_t xb_b = (size_t)NROWS * IN_F;        // 33,554,432
  const size_t rb_b = (size_t)OUT_F * IN_F;        // 16,777,216
  const size_t s_b = (size_t)NROWS * 9 * 4;        // 294,912
  const size_t ps_b = (size_t)2 * NROWS * 9 * 4;   // 589,824

  if (ws_size >= xb_b + rb_b + s_b + ps_b) {
    unsigned char* xb = (unsigned char*)d_ws;
    unsigned char* rb = xb + xb_b;
    float* s = (float*)(rb + rb_b);
    float* ps = (float*)((unsigned char*)s + s_b);
    hipLaunchKernelGGL(xqs_mfma, dim3(1024), dim3(256), 0, stream, x, cp, xb, ps);
    hipLaunchKernelGGL(s_reduce2, dim3(32), dim3(256), 0, stream, ps, s);
    hipLaunchKernelGGL(rq, dim3(4096), dim3(256), 0, stream, resid, rb);
    // (8192/256) * (4096/128) = 32*32 = 1024 blocks, 512 threads
    hipLaunchKernelGGL(gemm_fp8, dim3(1024), dim3(512), 0, stream, xb, rb, s, bias, out);
  } else {
    hipLaunchKernelGGL(fallback_gemm, dim3((NROWS / 64) * (OUT_F / 64)), dim3(256), 0,
                       stream, x, cp, resid, bias, out);
  }
}